// Round 1
// baseline (173.712 us; speedup 1.0000x reference)
//
#include <hip/hip_runtime.h>
#include <math.h>

#define N_ATOM 6144
#define N_FLAT (3 * N_ATOM)   // 18432

// ws layout:
//   float ws_f[0] : pair-penalty sum over full NxN (incl. diagonal)
//   float ws_f[1] : sum(x)
//   float ws_f[2] : sum(x^2)
//   float ws_f[3..6] : order-stat values at ranks 4607, 4608, 13823, 13824
//   int   counts[N_FLAT] starting at byte offset 32
#define WS_COUNT_OFF 8            // in floats/ints
#define WS_ZERO_BYTES (32 + N_FLAT * 4)

__device__ __forceinline__ float block_reduce_to_t0(float v, float* w4) {
    for (int o = 32; o; o >>= 1) v += __shfl_down(v, o, 64);
    int lane = threadIdx.x & 63, wid = threadIdx.x >> 6;
    if (lane == 0) w4[wid] = v;
    __syncthreads();
    return w4[0] + w4[1] + w4[2] + w4[3];   // valid everywhere after sync
}

// ---------------- sum / sumsq ----------------
__global__ __launch_bounds__(256) void sum_kernel(const float* __restrict__ x,
                                                  float* __restrict__ ws_f) {
    int i = blockIdx.x * 256 + threadIdx.x;          // grid = 72 blocks exactly
    float v = x[i];
    float s = v, s2 = v * v;
    for (int o = 32; o; o >>= 1) {
        s  += __shfl_down(s,  o, 64);
        s2 += __shfl_down(s2, o, 64);
    }
    __shared__ float a[4], b[4];
    int lane = threadIdx.x & 63, wid = threadIdx.x >> 6;
    if (lane == 0) { a[wid] = s; b[wid] = s2; }
    __syncthreads();
    if (threadIdx.x == 0) {
        atomicAdd(&ws_f[1], a[0] + a[1] + a[2] + a[3]);
        atomicAdd(&ws_f[2], b[0] + b[1] + b[2] + b[3]);
    }
}

// ---------------- pairwise penalty (full NxN, diagonal corrected later) ----
__global__ __launch_bounds__(256) void pair_kernel(const float* __restrict__ g,
                                                   float* __restrict__ ws_f) {
    __shared__ float sj[768];       // 256 points * 3 coords, flat
    __shared__ float w4[4];
    const int t  = threadIdx.x;
    const int i  = blockIdx.x * 256 + t;     // blockIdx.x in [0,24)
    const int jb = blockIdx.y * 256;         // blockIdx.y in [0,24)

    const float xi = g[3 * i + 0];
    const float yi = g[3 * i + 1];
    const float zi = g[3 * i + 2];

    for (int k = t; k < 768; k += 256) sj[k] = g[jb * 3 + k];
    __syncthreads();

    float acc = 0.f;
    #pragma unroll 8
    for (int jj = 0; jj < 256; ++jj) {
        float dx = xi - sj[3 * jj + 0];
        float dy = yi - sj[3 * jj + 1];
        float dz = zi - sj[3 * jj + 2];
        float sq = dx * dx + dy * dy + dz * dz;
        float d  = sqrtf(sq);
        acc += fmaxf(0.8f - d, 0.f);
    }

    float bsum = block_reduce_to_t0(acc, w4);
    if (t == 0) atomicAdd(&ws_f[0], bsum);
}

// ---------------- exact tie-broken ranks (counts = permutation of 0..n-1) --
__global__ __launch_bounds__(256) void count_kernel(const float* __restrict__ x,
                                                    int* __restrict__ counts) {
    const int JC = 2304;                     // 18432 / 8
    __shared__ float sj[JC];
    const int t     = threadIdx.x;
    const int i     = blockIdx.x * 256 + t;  // blockIdx.x in [0,72)
    const int jbase = blockIdx.y * JC;       // blockIdx.y in [0,8)

    const float xi = x[i];
    for (int k = t; k < JC; k += 256) sj[k] = x[jbase + k];
    __syncthreads();

    int c = 0;
    #pragma unroll 8
    for (int jj = 0; jj < JC; ++jj) {
        float xj = sj[jj];
        c += (xj < xi) ? 1 : 0;
        c += (xj == xi && (jbase + jj) < i) ? 1 : 0;
    }
    atomicAdd(&counts[i], c);
}

// ---------------- pick the 4 order statistics ----------------
__global__ __launch_bounds__(256) void select_kernel(const float* __restrict__ x,
                                                     const int* __restrict__ counts,
                                                     float* __restrict__ ws_f) {
    int i = blockIdx.x * 256 + threadIdx.x;
    int c = counts[i];
    float v = x[i];
    if (c == 4607)  ws_f[3] = v;
    if (c == 4608)  ws_f[4] = v;
    if (c == 13823) ws_f[5] = v;
    if (c == 13824) ws_f[6] = v;
}

// ---------------- finalize ----------------
__global__ void final_kernel(const float* __restrict__ ws_f, float* __restrict__ out) {
    if (threadIdx.x != 0) return;
    const float n_pairs = (float)((long long)N_ATOM * (N_ATOM - 1) / 2);
    float pair = (ws_f[0] - (float)N_ATOM * 0.8f) * 0.5f / n_pairs;

    const float n = (float)N_FLAT;
    float sum = ws_f[1], sumsq = ws_f[2];
    float var = (sumsq - sum * sum / n) / (n - 1.0f);
    float stdv = sqrtf(var);
    float sp = stdv - 1.75f; sp *= sp;

    float q1 = ws_f[3] + 0.75f * (ws_f[4] - ws_f[3]);
    float q3 = ws_f[5] + 0.25f * (ws_f[6] - ws_f[5]);
    float iq = (q3 - q1) - 2.45f; iq *= iq;

    out[0] = pair + sp + iq;
}

extern "C" void kernel_launch(void* const* d_in, const int* in_sizes, int n_in,
                              void* d_out, int out_size, void* d_ws, size_t ws_size,
                              hipStream_t stream) {
    const float* x = (const float*)d_in[0];   // flatten_geom, 18432 f32
    float* out  = (float*)d_out;
    float* ws_f = (float*)d_ws;
    int*   cnt  = (int*)d_ws + WS_COUNT_OFF;

    hipMemsetAsync(d_ws, 0, WS_ZERO_BYTES, stream);

    sum_kernel<<<72, 256, 0, stream>>>(x, ws_f);
    pair_kernel<<<dim3(24, 24), 256, 0, stream>>>(x, ws_f);
    count_kernel<<<dim3(72, 8), 256, 0, stream>>>(x, cnt);
    select_kernel<<<72, 256, 0, stream>>>(x, cnt, ws_f);
    final_kernel<<<1, 64, 0, stream>>>(ws_f, out);
}

// Round 2
// 123.555 us; speedup vs baseline: 1.4059x; 1.4059x over previous
//
#include <hip/hip_runtime.h>
#include <math.h>

#define N_ATOM 6144
#define N_FLAT (3 * N_ATOM)   // 18432
#define NBINS  4096

// ws layout (floats/ints):
//   ws_f[0] : pair-penalty sum over full NxN (incl. diagonal, both triangles)
//   ws_f[1] : sum(x)
//   ws_f[2] : sum(x^2)
//   int hist[NBINS] at int offset 8
#define WS_HIST_OFF 8
#define WS_ZERO_BYTES (32 + NBINS * 4)

__device__ __forceinline__ int bin_of(float v) {
    int b = (int)((v + 8.0f) * 256.0f);     // width 1/256 over [-8,8]
    return min(max(b, 0), NBINS - 1);
}

// ---------------- pairwise penalty (full NxN, diagonal corrected later) ----
// 2 i-points per thread, 128-point j tile. grid (12, 48).
__global__ __launch_bounds__(256) void pair_kernel(const float* __restrict__ g,
                                                   float* __restrict__ ws_f) {
    __shared__ float sx[128], sy[128], sz[128];
    __shared__ float w4[4];
    const int t  = threadIdx.x;
    const int i0 = blockIdx.x * 512 + t;      // second point: i0 + 256
    const int jb = blockIdx.y * 128;

    if (t < 128) {
        int j = jb + t;
        sx[t] = g[3 * j + 0];
        sy[t] = g[3 * j + 1];
        sz[t] = g[3 * j + 2];
    }
    const float x0 = g[3 * i0 + 0], y0 = g[3 * i0 + 1], z0 = g[3 * i0 + 2];
    const int   i1 = i0 + 256;
    const float x1 = g[3 * i1 + 0], y1 = g[3 * i1 + 1], z1 = g[3 * i1 + 2];
    __syncthreads();

    float a0 = 0.f, a1 = 0.f;
    #pragma unroll 8
    for (int j = 0; j < 128; ++j) {
        float bx = sx[j], by = sy[j], bz = sz[j];
        float dx0 = x0 - bx, dy0 = y0 - by, dz0 = z0 - bz;
        float dx1 = x1 - bx, dy1 = y1 - by, dz1 = z1 - bz;
        float s0 = dx0 * dx0 + dy0 * dy0 + dz0 * dz0;
        float s1 = dx1 * dx1 + dy1 * dy1 + dz1 * dz1;
        a0 += fmaxf(0.8f - sqrtf(s0), 0.f);
        a1 += fmaxf(0.8f - sqrtf(s1), 0.f);
    }

    float v = a0 + a1;
    for (int o = 32; o; o >>= 1) v += __shfl_down(v, o, 64);
    int lane = t & 63, wid = t >> 6;
    if (lane == 0) w4[wid] = v;
    __syncthreads();
    if (t == 0) atomicAdd(&ws_f[0], w4[0] + w4[1] + w4[2] + w4[3]);
}

// ---------------- histogram + sum/sumsq (grid 72) ----------------
__global__ __launch_bounds__(256) void hist_kernel(const float* __restrict__ x,
                                                   float* __restrict__ ws_f,
                                                   int* __restrict__ hist) {
    int i = blockIdx.x * 256 + threadIdx.x;
    float v = x[i];
    atomicAdd(&hist[bin_of(v)], 1);

    float s = v, s2 = v * v;
    for (int o = 32; o; o >>= 1) {
        s  += __shfl_down(s,  o, 64);
        s2 += __shfl_down(s2, o, 64);
    }
    __shared__ float a[4], b[4];
    int lane = threadIdx.x & 63, wid = threadIdx.x >> 6;
    if (lane == 0) { a[wid] = s; b[wid] = s2; }
    __syncthreads();
    if (threadIdx.x == 0) {
        atomicAdd(&ws_f[1], a[0] + a[1] + a[2] + a[3]);
        atomicAdd(&ws_f[2], b[0] + b[1] + b[2] + b[3]);
    }
}

// ---------------- scan + exact select + finalize (1 block, 256 thr) -------
#define CAND_CAP 512
__global__ __launch_bounds__(256) void mega_kernel(const float* __restrict__ x,
                                                   const int* __restrict__ hist,
                                                   const float* __restrict__ ws_f,
                                                   float* __restrict__ out) {
    __shared__ int   cum[NBINS];
    __shared__ int   part[256];
    __shared__ float candv[4][CAND_CAP];
    __shared__ int   candi[4][CAND_CAP];
    __shared__ int   cnum[4];
    __shared__ int   tbin[4], trank[4];
    __shared__ float qv[4];

    const int t = threadIdx.x;
    const int ranks[4] = {4607, 4608, 13823, 13824};

    // per-thread 16-bin local sums
    int h[16]; int s = 0;
    #pragma unroll
    for (int k = 0; k < 16; ++k) { h[k] = hist[t * 16 + k]; s += h[k]; }
    part[t] = s;
    if (t < 4) cnum[t] = 0;
    __syncthreads();
    // Hillis-Steele inclusive scan over 256 partials
    for (int o = 1; o < 256; o <<= 1) {
        int v = part[t];
        if (t >= o) v += part[t - o];
        __syncthreads();
        part[t] = v;
        __syncthreads();
    }
    int run = (t ? part[t - 1] : 0);
    #pragma unroll
    for (int k = 0; k < 16; ++k) { run += h[k]; cum[t * 16 + k] = run; } // inclusive
    __syncthreads();

    // locate bin + within-bin rank for each target
    if (t < 4) {
        int r = ranks[t];
        int lo = 0, hi = NBINS - 1;
        while (lo < hi) { int mid = (lo + hi) >> 1; if (cum[mid] > r) hi = mid; else lo = mid + 1; }
        tbin[t]  = lo;
        trank[t] = r - (cum[lo] - hist[lo]);   // exclusive base
    }
    __syncthreads();

    // extract candidates in target bins
    for (int i = t; i < N_FLAT; i += 256) {
        float v = x[i];
        int b = bin_of(v);
        #pragma unroll
        for (int q = 0; q < 4; ++q) {
            if (b == tbin[q]) {
                int p = atomicAdd(&cnum[q], 1);
                if (p < CAND_CAP) { candv[q][p] = v; candi[q][p] = i; }
            }
        }
    }
    __syncthreads();

    // exact tie-broken rank within each candidate list
    for (int q = 0; q < 4; ++q) {
        int m = min(cnum[q], CAND_CAP);
        int r = trank[q];
        for (int k = t; k < m; k += 256) {
            float vk = candv[q][k]; int ik = candi[q][k];
            int less = 0;
            for (int j = 0; j < m; ++j) {
                float vj = candv[q][j];
                less += (vj < vk || (vj == vk && candi[q][j] < ik)) ? 1 : 0;
            }
            if (less == r) qv[q] = vk;
        }
    }
    __syncthreads();

    if (t == 0) {
        const float n_pairs = (float)((long long)N_ATOM * (N_ATOM - 1) / 2);
        float pair = (ws_f[0] - (float)N_ATOM * 0.8f) * 0.5f / n_pairs;

        const float n = (float)N_FLAT;
        float sum = ws_f[1], sumsq = ws_f[2];
        float var  = (sumsq - sum * sum / n) / (n - 1.0f);
        float stdv = sqrtf(var);
        float sp = stdv - 1.75f; sp *= sp;

        float q1 = qv[0] + 0.75f * (qv[1] - qv[0]);
        float q3 = qv[2] + 0.25f * (qv[3] - qv[2]);
        float iq = (q3 - q1) - 2.45f; iq *= iq;

        out[0] = pair + sp + iq;
    }
}

extern "C" void kernel_launch(void* const* d_in, const int* in_sizes, int n_in,
                              void* d_out, int out_size, void* d_ws, size_t ws_size,
                              hipStream_t stream) {
    const float* x = (const float*)d_in[0];   // 18432 f32
    float* out  = (float*)d_out;
    float* ws_f = (float*)d_ws;
    int*   hist = (int*)d_ws + WS_HIST_OFF;

    hipMemsetAsync(d_ws, 0, WS_ZERO_BYTES, stream);

    pair_kernel<<<dim3(12, 48), 256, 0, stream>>>(x, ws_f);
    hist_kernel<<<72, 256, 0, stream>>>(x, ws_f, hist);
    mega_kernel<<<1, 256, 0, stream>>>(x, hist, ws_f, out);
}

// Round 3
// 117.765 us; speedup vs baseline: 1.4751x; 1.0492x over previous
//
#include <hip/hip_runtime.h>
#include <math.h>

#define NA    6144
#define NF    18432        // 3 * NA
#define NBINS 4096
#define NB    512          // blocks in big_kernel
#define SLICE 36           // NF / NB
#define PCAP  16           // per-block per-target candidate cap (expected ~0.06)
#define CCAP  256          // compact candidate cap in final_kernel

// ws layout in 4-byte words:
#define W_PAIR  0                       // [NB] float : per-block pair partial
#define W_SUM   512                     // float
#define W_SUMSQ 513                     // float
#define W_TRANK 516                     // [4] int : within-bin target ranks
#define W_CNT   520                     // [4*NB] int : per-block per-target counts
#define W_CANDV (W_CNT + 4*NB)          // [4*NB*PCAP] float
#define W_CANDI (W_CANDV + 4*NB*PCAP)   // [4*NB*PCAP] int

__device__ __forceinline__ int bin_of(float v) {
    int b = (int)((v + 8.0f) * 256.0f);     // width 1/256 over [-8, 8]
    return min(max(b, 0), NBINS - 1);
}

__global__ __launch_bounds__(256) void big_kernel(const float* __restrict__ x,
                                                  float* __restrict__ ws) {
    __shared__ int    hist[NBINS];      // becomes inclusive cumsum after scan
    __shared__ int    part[256];
    __shared__ float4 sj[96];
    __shared__ int    tbin[4], trank[4], lcnt[4];
    __shared__ float  lv[4][PCAP];
    __shared__ int    li[4][PCAP];
    __shared__ float  w4[4], w4s[4], w4s2[4];

    const int t = threadIdx.x;
    const int b = blockIdx.x;

    // ---- 1. zero LDS hist + counters ----
    #pragma unroll
    for (int k = 0; k < 16; ++k) hist[t * 16 + k] = 0;
    if (t < 4) lcnt[t] = 0;
    __syncthreads();

    // ---- 2. full-array private histogram (+ sum/sumsq in block 0) ----
    float s = 0.f, s2 = 0.f;
    for (int i = t; i < NF; i += 256) {
        float v = x[i];
        atomicAdd(&hist[bin_of(v)], 1);
        if (b == 0) { s += v; s2 += v * v; }
    }
    __syncthreads();

    // ---- 3. in-place inclusive scan of hist (256 x 16) ----
    int h[16]; int ls = 0;
    #pragma unroll
    for (int k = 0; k < 16; ++k) { h[k] = hist[t * 16 + k]; ls += h[k]; }
    part[t] = ls;
    __syncthreads();
    for (int o = 1; o < 256; o <<= 1) {
        int v = part[t];
        if (t >= o) v += part[t - o];
        __syncthreads();
        part[t] = v;
        __syncthreads();
    }
    int run = t ? part[t - 1] : 0;
    #pragma unroll
    for (int k = 0; k < 16; ++k) { run += h[k]; hist[t * 16 + k] = run; }
    __syncthreads();

    // ---- 4. locate target bins + within-bin ranks ----
    if (t < 4) {
        const int ranks[4] = {4607, 4608, 13823, 13824};
        int r = ranks[t];
        int lo = 0, hi = NBINS - 1;
        while (lo < hi) { int mid = (lo + hi) >> 1; if (hist[mid] > r) hi = mid; else lo = mid + 1; }
        tbin[t]  = lo;
        trank[t] = r - (lo ? hist[lo - 1] : 0);
        if (b == 0) ((int*)ws)[W_TRANK + t] = trank[t];
    }
    __syncthreads();

    // ---- 5. extract candidates from this block's slice ----
    if (t < SLICE) {
        int i = b * SLICE + t;
        float v = x[i];
        int bi = bin_of(v);
        #pragma unroll
        for (int q = 0; q < 4; ++q) {
            if (bi == tbin[q]) {
                int p = atomicAdd(&lcnt[q], 1);
                if (p < PCAP) { lv[q][p] = v; li[q][p] = i; }
            }
        }
    }
    __syncthreads();
    if (t < 4 * PCAP) {
        int q = t / PCAP, p = t % PCAP;
        int c = min(lcnt[q], PCAP);
        if (p < c) {
            ws[W_CANDV + (q * NB + b) * PCAP + p] = lv[q][p];
            ((int*)ws)[W_CANDI + (q * NB + b) * PCAP + p] = li[q][p];
        }
        if (p == 0) ((int*)ws)[W_CNT + q * NB + b] = c;
    }

    // ---- 6. pair-penalty tile: ic = b>>6 (8 i-chunks of 768), jc = b&63 (64 j-chunks of 96)
    const int ic = b >> 6, jc = b & 63;
    const int i0 = ic * 768 + t;
    const float x0 = x[3*i0+0],       y0 = x[3*i0+1],       z0 = x[3*i0+2];
    const float x1 = x[3*(i0+256)+0], y1 = x[3*(i0+256)+1], z1 = x[3*(i0+256)+2];
    const float x2 = x[3*(i0+512)+0], y2 = x[3*(i0+512)+1], z2 = x[3*(i0+512)+2];
    if (t < 96) {
        int j = jc * 96 + t;
        sj[t] = make_float4(x[3*j+0], x[3*j+1], x[3*j+2], 0.f);
    }
    __syncthreads();

    float a0 = 0.f, a1 = 0.f, a2 = 0.f;
    #pragma unroll 8
    for (int j = 0; j < 96; ++j) {
        float4 p = sj[j];
        float dx0 = x0 - p.x, dy0 = y0 - p.y, dz0 = z0 - p.z;
        float dx1 = x1 - p.x, dy1 = y1 - p.y, dz1 = z1 - p.z;
        float dx2 = x2 - p.x, dy2 = y2 - p.y, dz2 = z2 - p.z;
        float s0 = dx0*dx0 + dy0*dy0 + dz0*dz0;
        float s1 = dx1*dx1 + dy1*dy1 + dz1*dz1;
        float s2_ = dx2*dx2 + dy2*dy2 + dz2*dz2;
        a0 += fmaxf(0.8f - sqrtf(s0), 0.f);
        a1 += fmaxf(0.8f - sqrtf(s1), 0.f);
        a2 += fmaxf(0.8f - sqrtf(s2_), 0.f);
    }

    float v = a0 + a1 + a2;
    for (int o = 32; o; o >>= 1) v += __shfl_down(v, o, 64);
    int lane = t & 63, wid = t >> 6;
    if (lane == 0) w4[wid] = v;
    __syncthreads();
    if (t == 0) ws[W_PAIR + b] = w4[0] + w4[1] + w4[2] + w4[3];

    // ---- 7. block 0: reduce sum/sumsq, plain store ----
    if (b == 0) {
        for (int o = 32; o; o >>= 1) {
            s  += __shfl_down(s,  o, 64);
            s2 += __shfl_down(s2, o, 64);
        }
        if (lane == 0) { w4s[wid] = s; w4s2[wid] = s2; }
        __syncthreads();
        if (t == 0) {
            ws[W_SUM]   = w4s[0] + w4s[1] + w4s[2] + w4s[3];
            ws[W_SUMSQ] = w4s2[0] + w4s2[1] + w4s2[2] + w4s2[3];
        }
    }
}

__global__ __launch_bounds__(256) void final_kernel(const float* __restrict__ ws,
                                                    float* __restrict__ out) {
    __shared__ float cv[4][CCAP];
    __shared__ int   ci[4][CCAP];
    __shared__ int   tot[4];
    __shared__ float qv[4];
    __shared__ float w4[4];

    const int t = threadIdx.x;
    if (t < 4) tot[t] = 0;
    __syncthreads();

    const int*   cnt   = (const int*)ws + W_CNT;
    const float* candv = ws + W_CANDV;
    const int*   candi = (const int*)ws + W_CANDI;

    // gather per-block candidate lists into compact LDS lists
    #pragma unroll
    for (int q = 0; q < 4; ++q) {
        for (int b = t; b < NB; b += 256) {
            int c = cnt[q * NB + b];
            if (c > 0) {
                int pos = atomicAdd(&tot[q], c);
                for (int k = 0; k < c; ++k) {
                    int p = pos + k;
                    if (p < CCAP) {
                        cv[q][p] = candv[(q * NB + b) * PCAP + k];
                        ci[q][p] = candi[(q * NB + b) * PCAP + k];
                    }
                }
            }
        }
    }
    __syncthreads();

    // exact tie-broken rank within each candidate list
    for (int q = 0; q < 4; ++q) {
        int m = min(tot[q], CCAP);
        int r = ((const int*)ws)[W_TRANK + q];
        for (int k = t; k < m; k += 256) {
            float vk = cv[q][k]; int ik = ci[q][k];
            int less = 0;
            for (int j = 0; j < m; ++j) {
                float vj = cv[q][j];
                less += (vj < vk || (vj == vk && ci[q][j] < ik)) ? 1 : 0;
            }
            if (less == r) qv[q] = vk;
        }
    }

    // sum the 512 pair partials
    float v = ws[W_PAIR + t] + ws[W_PAIR + t + 256];
    for (int o = 32; o; o >>= 1) v += __shfl_down(v, o, 64);
    int lane = t & 63, wid = t >> 6;
    if (lane == 0) w4[wid] = v;
    __syncthreads();

    if (t == 0) {
        float pair_sum = w4[0] + w4[1] + w4[2] + w4[3];
        const float n_pairs = (float)((long long)NA * (NA - 1) / 2);
        float pair = (pair_sum - (float)NA * 0.8f) * 0.5f / n_pairs;

        const float n = (float)NF;
        float sum = ws[W_SUM], sumsq = ws[W_SUMSQ];
        float var  = (sumsq - sum * sum / n) / (n - 1.0f);
        float stdv = sqrtf(var);
        float sp = stdv - 1.75f; sp *= sp;

        float q1 = qv[0] + 0.75f * (qv[1] - qv[0]);
        float q3 = qv[2] + 0.25f * (qv[3] - qv[2]);
        float iq = (q3 - q1) - 2.45f; iq *= iq;

        out[0] = pair + sp + iq;
    }
}

extern "C" void kernel_launch(void* const* d_in, const int* in_sizes, int n_in,
                              void* d_out, int out_size, void* d_ws, size_t ws_size,
                              hipStream_t stream) {
    const float* x = (const float*)d_in[0];   // 18432 f32
    float* out = (float*)d_out;
    float* ws  = (float*)d_ws;

    big_kernel<<<NB, 256, 0, stream>>>(x, ws);
    final_kernel<<<1, 256, 0, stream>>>(ws, out);
}